// Round 1
// baseline (4928.206 us; speedup 1.0000x reference)
//
#include <hip/hip_runtime.h>
#include <hip/hip_bf16.h>
#include <cstdint>
#include <cstddef>

#define BATCH  256
#define HID    1024
#define TSTEPS 128

typedef __attribute__((ext_vector_type(8))) short bf16x8;   // 8 bf16 (4 VGPRs)
typedef __attribute__((ext_vector_type(4))) float f32x4;

__device__ inline float bf2f(__hip_bfloat16 h) { return __bfloat162float(h); }

// One-shot prep: split w_hh and h0 into bf16 hi/lo, copy fp32 h master,
// pre-fill out with b_ffn (y partials are atomically accumulated on top).
__global__ void prep_kernel(const float* __restrict__ vectors,
                            const float* __restrict__ w_hh,
                            const float* __restrict__ b_ffn,
                            float* __restrict__ h_master,
                            __hip_bfloat16* __restrict__ h_hi0,
                            __hip_bfloat16* __restrict__ h_lo0,
                            __hip_bfloat16* __restrict__ w_hi,
                            __hip_bfloat16* __restrict__ w_lo,
                            float* __restrict__ out)
{
    const long long stride = (long long)gridDim.x * blockDim.x;
    const long long idx = (long long)blockIdx.x * blockDim.x + threadIdx.x;

    const long long NW = 3LL * HID * HID;
    for (long long i = idx; i < NW; i += stride) {
        float w = w_hh[i];
        __hip_bfloat16 hi = __float2bfloat16(w);
        w_hi[i] = hi;
        w_lo[i] = __float2bfloat16(w - bf2f(hi));
    }
    const long long NH = (long long)BATCH * HID;
    for (long long i = idx; i < NH; i += stride) {
        float h = vectors[i];
        __hip_bfloat16 hi = __float2bfloat16(h);
        h_master[i] = h;
        h_hi0[i] = hi;
        h_lo0[i] = __float2bfloat16(h - bf2f(hi));
    }
    const float bf = b_ffn[0];
    for (long long i = idx; i < (long long)BATCH * TSTEPS; i += stride) out[i] = bf;
}

// One GRU time step.
// Grid: 256 blocks = 64 j-tiles (16 cols of H; 48 rows of w_hh across 3 gates)
//                  x 4 m-tiles (64 batch rows). Same-j blocks share an XCD.
// Block: 256 thr = 4 waves; wave w owns m-subtile of 16 rows x all 3 gate n-tiles.
__global__ __launch_bounds__(256)
void gru_step_kernel(const float* __restrict__ w_ih,
                     const float* __restrict__ b_ih,
                     const float* __restrict__ b_hh,
                     const float* __restrict__ w_ffn,
                     const float* __restrict__ first_input,
                     const __hip_bfloat16* __restrict__ h_hi_cur,
                     const __hip_bfloat16* __restrict__ h_lo_cur,
                     __hip_bfloat16* __restrict__ h_hi_nxt,
                     __hip_bfloat16* __restrict__ h_lo_nxt,
                     float* __restrict__ h_master,
                     const __hip_bfloat16* __restrict__ w_hi,
                     const __hip_bfloat16* __restrict__ w_lo,
                     float* __restrict__ out,
                     int t)
{
    const int blk  = blockIdx.x;
    const int g    = blk & 7;          // XCD via blockIdx % 8 round-robin
    const int ii   = blk >> 3;         // 0..31
    const int j_tile = g * 8 + (ii & 7);   // 0..63 -> same-j on same XCD
    const int m_tile = ii >> 3;            // 0..3
    const int wave = threadIdx.x >> 6;
    const int lane = threadIdx.x & 63;
    const int l15  = lane & 15;
    const int kgrp = lane >> 4;
    const int m_sub  = m_tile * 64 + wave * 16;
    const int j_base = j_tile * 16;

    // A operand (h): row = lane&15, k = (lane>>4)*8 + j, 16B contiguous along K
    const size_t aoff = (size_t)(m_sub + l15) * HID + kgrp * 8;
    const bf16x8* __restrict__ pAhi = (const bf16x8*)(h_hi_cur + aoff);
    const bf16x8* __restrict__ pAlo = (const bf16x8*)(h_lo_cur + aoff);
    // B operand (w_hh rows): col = lane&15 -> w row, same k mapping
    size_t boff0 = (size_t)(0 * HID + j_base + l15) * HID + kgrp * 8;
    size_t boff1 = (size_t)(1 * HID + j_base + l15) * HID + kgrp * 8;
    size_t boff2 = (size_t)(2 * HID + j_base + l15) * HID + kgrp * 8;

    f32x4 acc0 = {0.f, 0.f, 0.f, 0.f};
    f32x4 acc1 = acc0, acc2 = acc0;

    #pragma unroll 2
    for (int k0 = 0; k0 < HID; k0 += 32) {
        const int kv = k0 >> 3;  // bf16x8 index
        bf16x8 ahi = pAhi[kv];
        bf16x8 alo = pAlo[kv];
        bf16x8 bhi0 = *(const bf16x8*)(w_hi + boff0 + k0);
        bf16x8 bhi1 = *(const bf16x8*)(w_hi + boff1 + k0);
        bf16x8 bhi2 = *(const bf16x8*)(w_hi + boff2 + k0);
        bf16x8 blo0 = *(const bf16x8*)(w_lo + boff0 + k0);
        bf16x8 blo1 = *(const bf16x8*)(w_lo + boff1 + k0);
        bf16x8 blo2 = *(const bf16x8*)(w_lo + boff2 + k0);
        // interleave across the 3 accumulators to spread dep chains
        acc0 = __builtin_amdgcn_mfma_f32_16x16x32_bf16(ahi, bhi0, acc0, 0, 0, 0);
        acc1 = __builtin_amdgcn_mfma_f32_16x16x32_bf16(ahi, bhi1, acc1, 0, 0, 0);
        acc2 = __builtin_amdgcn_mfma_f32_16x16x32_bf16(ahi, bhi2, acc2, 0, 0, 0);
        acc0 = __builtin_amdgcn_mfma_f32_16x16x32_bf16(ahi, blo0, acc0, 0, 0, 0);
        acc1 = __builtin_amdgcn_mfma_f32_16x16x32_bf16(ahi, blo1, acc1, 0, 0, 0);
        acc2 = __builtin_amdgcn_mfma_f32_16x16x32_bf16(ahi, blo2, acc2, 0, 0, 0);
        acc0 = __builtin_amdgcn_mfma_f32_16x16x32_bf16(alo, bhi0, acc0, 0, 0, 0);
        acc1 = __builtin_amdgcn_mfma_f32_16x16x32_bf16(alo, bhi1, acc1, 0, 0, 0);
        acc2 = __builtin_amdgcn_mfma_f32_16x16x32_bf16(alo, bhi2, acc2, 0, 0, 0);
    }

    // Epilogue: gates + h update + y partial. C/D layout: col=lane&15, row=(lane>>4)*4+reg
    const int j = j_base + l15;
    const float bhr = b_hh[j], bhz = b_hh[HID + j], bhn = b_hh[2 * HID + j];
    const float wir = w_ih[j], wiz = w_ih[HID + j], win = w_ih[2 * HID + j];
    const float bir = b_ih[j], biz = b_ih[HID + j], bin_ = b_ih[2 * HID + j];
    const float wf = w_ffn[j];
    const float x0 = first_input[0];

    #pragma unroll
    for (int r = 0; r < 4; ++r) {
        const int brow = m_sub + kgrp * 4 + r;
        const float x = (t == 0) ? x0 : out[(size_t)brow * TSTEPS + (t - 1)];
        const float ghr = acc0[r] + bhr;
        const float ghz = acc1[r] + bhz;
        const float ghn = acc2[r] + bhn;   // includes b_hh: n = tanh(gi_n + r*gh_n)
        const float gir = fmaf(x, wir, bir);
        const float giz = fmaf(x, wiz, biz);
        const float gin = fmaf(x, win, bin_);
        const float rg = 1.f / (1.f + expf(-(gir + ghr)));
        const float zg = 1.f / (1.f + expf(-(giz + ghz)));
        const float ng = tanhf(fmaf(rg, ghn, gin));
        const float hold = h_master[(size_t)brow * HID + j];
        const float hnew = (1.f - zg) * ng + zg * hold;
        h_master[(size_t)brow * HID + j] = hnew;
        const __hip_bfloat16 hi = __float2bfloat16(hnew);
        h_hi_nxt[(size_t)brow * HID + j] = hi;
        h_lo_nxt[(size_t)brow * HID + j] = __float2bfloat16(hnew - bf2f(hi));
        // y partial: reduce this block's 16 cols across the 16-lane group
        float py = hnew * wf;
        py += __shfl_xor(py, 1);
        py += __shfl_xor(py, 2);
        py += __shfl_xor(py, 4);
        py += __shfl_xor(py, 8);
        if (l15 == 0) atomicAdd(&out[(size_t)brow * TSTEPS + t], py);
    }
}

extern "C" void kernel_launch(void* const* d_in, const int* in_sizes, int n_in,
                              void* d_out, int out_size, void* d_ws, size_t ws_size,
                              hipStream_t stream)
{
    const float* vectors     = (const float*)d_in[0];
    const float* w_ih        = (const float*)d_in[1];
    const float* w_hh        = (const float*)d_in[2];
    const float* b_ih        = (const float*)d_in[3];
    const float* b_hh        = (const float*)d_in[4];
    const float* w_ffn       = (const float*)d_in[5];
    const float* b_ffn       = (const float*)d_in[6];
    const float* first_input = (const float*)d_in[7];
    float* out = (float*)d_out;

    // workspace carve (~15.7 MB total)
    char* p = (char*)d_ws;
    float* h_master = (float*)p;                 p += (size_t)BATCH * HID * 4;
    __hip_bfloat16* h_hi[2];
    __hip_bfloat16* h_lo[2];
    h_hi[0] = (__hip_bfloat16*)p;                p += (size_t)BATCH * HID * 2;
    h_lo[0] = (__hip_bfloat16*)p;                p += (size_t)BATCH * HID * 2;
    h_hi[1] = (__hip_bfloat16*)p;                p += (size_t)BATCH * HID * 2;
    h_lo[1] = (__hip_bfloat16*)p;                p += (size_t)BATCH * HID * 2;
    __hip_bfloat16* w_hi = (__hip_bfloat16*)p;   p += (size_t)3 * HID * HID * 2;
    __hip_bfloat16* w_lo = (__hip_bfloat16*)p;   p += (size_t)3 * HID * HID * 2;

    prep_kernel<<<512, 256, 0, stream>>>(vectors, w_hh, b_ffn, h_master,
                                         h_hi[0], h_lo[0], w_hi, w_lo, out);
    for (int t = 0; t < TSTEPS; ++t) {
        const int c = t & 1, n = c ^ 1;
        gru_step_kernel<<<256, 256, 0, stream>>>(
            w_ih, b_ih, b_hh, w_ffn, first_input,
            h_hi[c], h_lo[c], h_hi[n], h_lo[n], h_master,
            w_hi, w_lo, out, t);
    }
}